// Round 1
// baseline (359.168 us; speedup 1.0000x reference)
//
#include <hip/hip_runtime.h>

typedef _Float16 f16;
typedef _Float16 f16x8 __attribute__((ext_vector_type(8)));
typedef _Float16 f16x4 __attribute__((ext_vector_type(4)));
typedef float f32x4 __attribute__((ext_vector_type(4)));
typedef float f32x16 __attribute__((ext_vector_type(16)));

constexpr int NB = 32, NS = 576, ND = 768, NG = 24;
constexpr int M_TOT = NB * NS;   // 18432
constexpr int N_TOT = 3 * ND;    // 2304

// ---------------- kernel 1: build W_allT (N_TOT x ND) f16 via LDS tile transpose ----------------
__global__ __launch_bounds__(256) void cast_w_t_kernel(const float* __restrict__ Wq,
                                                       const float* __restrict__ Wk,
                                                       const float* __restrict__ Wv,
                                                       f16* __restrict__ WT) {
  __shared__ float tile[64][65];
  int bt = blockIdx.x;                 // 0..431
  int ntile = bt / 12, ktile = bt % 12;
  const float* src = (ntile < 12) ? Wq : ((ntile < 24) ? Wk : Wv);
  int n0 = (ntile % 12) * 64, k0 = ktile * 64;
  int cc = threadIdx.x & 63, rr = threadIdx.x >> 6;
#pragma unroll
  for (int i = 0; i < 16; i++) {
    int k = rr + i * 4;
    tile[cc][k] = src[(size_t)(k0 + k) * ND + n0 + cc];
  }
  __syncthreads();
#pragma unroll
  for (int i = 0; i < 16; i++) {
    int n = rr + i * 4;
    WT[(size_t)(ntile * 64 + n) * ND + k0 + cc] = (f16)tile[n][cc];
  }
}

// ---------------- kernel 2: WcT hi/lo, j-split x4 per block; bc in block 768 ----------------
__global__ __launch_bounds__(256) void wcT_kernel(const float* __restrict__ Wq,
                                                  const float* __restrict__ Wk,
                                                  const float* __restrict__ bq,
                                                  const float* __restrict__ bk,
                                                  const float* __restrict__ W1,
                                                  const float* __restrict__ b1,
                                                  f16* __restrict__ WcT_hi,
                                                  f16* __restrict__ WcT_lo,
                                                  float* __restrict__ bc) {
  if (blockIdx.x == 768) {
    int c = threadIdx.x;
    if (c < 60) {
      float acc = b1[c];
      for (int j = 0; j < ND; j++)
        acc += bq[j] * W1[j * 60 + c] + bk[j] * W1[(ND + j) * 60 + c];
      bc[c] = acc;
    }
    return;
  }
  __shared__ float part[4][64];
  int r = blockIdx.x;                       // 0..767
  int wave = threadIdx.x >> 6, lane = threadIdx.x & 63;
  int c = (lane < 60) ? lane : 59;
  const float* wq = Wq + (size_t)r * ND;
  const float* wk = Wk + (size_t)r * ND;
  float acc = 0.f;
  int j0 = wave * 192;
  for (int j = j0; j < j0 + 192; j++)
    acc += wq[j] * W1[j * 60 + c] + wk[j] * W1[(ND + j) * 60 + c];
  part[wave][lane] = acc;
  __syncthreads();
  if (wave == 0 && lane < 60) {
    float v = part[0][lane] + part[1][lane] + part[2][lane] + part[3][lane];
    f16 hi = (f16)v;
    WcT_hi[(size_t)lane * ND + r] = hi;
    WcT_lo[(size_t)lane * ND + r] = (f16)(v - (float)hi);
  }
}

// ---------------- kernel 3: fused z1 MFMA + x cast + MLP tail + coord scatter ----------------
__global__ __launch_bounds__(256) void z1_fused_kernel(const float* __restrict__ x,
                                                       const f16* __restrict__ WcT_hi,
                                                       const f16* __restrict__ WcT_lo,
                                                       const float* __restrict__ bc,
                                                       const float* __restrict__ W2,
                                                       const float* __restrict__ b2,
                                                       const float* __restrict__ W3,
                                                       const float* __restrict__ b3,
                                                       f16* __restrict__ xb,
                                                       float* __restrict__ coords) {
  __shared__ float red[3][16][64];   // [wave-1][reg-idx][lane]
  __shared__ float htile[16][60];    // relu(z1) tile for this block's 16 rows
  int wave = threadIdx.x >> 6, lane = threadIdx.x & 63;
  int q = lane >> 4, r16 = lane & 15;
  int m0 = blockIdx.x * 16;
  int k0 = wave * 192;
  const float* xr = x + (size_t)(m0 + r16) * ND + k0;
  f16* xbr = xb + (size_t)(m0 + r16) * ND + k0;

  f32x4 acc[4];
#pragma unroll
  for (int nf = 0; nf < 4; nf++) acc[nf] = 0.f;

  for (int kk = 0; kk < 192; kk += 32) {
    int ko = kk + q * 8;
    float4 v0 = *(const float4*)(xr + ko);
    float4 v1 = *(const float4*)(xr + ko + 4);
    f16x8 a_hi, a_lo;
    float xv[8] = {v0.x, v0.y, v0.z, v0.w, v1.x, v1.y, v1.z, v1.w};
#pragma unroll
    for (int j = 0; j < 8; j++) {
      f16 h = (f16)xv[j];
      a_hi[j] = h;
      a_lo[j] = (f16)(xv[j] - (float)h);
    }
    *(f16x8*)(xbr + ko) = a_hi;      // fused fp32->f16 cast of x
    f16x8 b_hi[4], b_lo[4];
#pragma unroll
    for (int nf = 0; nf < 4; nf++) {
      size_t off = (size_t)(nf * 16 + r16) * ND + k0 + ko;
      b_hi[nf] = *(const f16x8*)(WcT_hi + off);
      b_lo[nf] = *(const f16x8*)(WcT_lo + off);
    }
#pragma unroll
    for (int nf = 0; nf < 4; nf++) {
      acc[nf] = __builtin_amdgcn_mfma_f32_16x16x32_f16(a_hi, b_hi[nf], acc[nf], 0, 0, 0);
      acc[nf] = __builtin_amdgcn_mfma_f32_16x16x32_f16(a_lo, b_hi[nf], acc[nf], 0, 0, 0);
      acc[nf] = __builtin_amdgcn_mfma_f32_16x16x32_f16(a_hi, b_lo[nf], acc[nf], 0, 0, 0);
    }
  }

  if (wave > 0) {
#pragma unroll
    for (int nf = 0; nf < 4; nf++)
#pragma unroll
      for (int r = 0; r < 4; r++) red[wave - 1][nf * 4 + r][lane] = acc[nf][r];
  }
  __syncthreads();
  if (wave == 0) {
#pragma unroll
    for (int nf = 0; nf < 4; nf++) {
      int col = nf * 16 + r16;
      if (col < 60) {
        float bcv = bc[col];
#pragma unroll
        for (int r = 0; r < 4; r++) {
          float v = acc[nf][r] + red[0][nf * 4 + r][lane] + red[1][nf * 4 + r][lane]
                  + red[2][nf * 4 + r][lane] + bcv;
          htile[q * 4 + r][col] = fmaxf(v, 0.f);
        }
      }
    }
  }
  __syncthreads();

  // MLP tail: wave w -> rows 4w..4w+3; lane c<60 owns layer-2 column c.
  int c = (lane < 60) ? lane : 59;
  float b2v = b2[c];
  float w30 = W3[c * 2 + 0], w31 = W3[c * 2 + 1];
#pragma unroll
  for (int rr = 0; rr < 4; rr++) {
    int row = wave * 4 + rr;
    float acc2 = b2v;
    for (int j = 0; j < 60; j++) acc2 = fmaf(htile[row][j], W2[j * 60 + c], acc2);
    float h2 = fmaxf(acc2, 0.f);
    float p0 = (lane < 60) ? h2 * w30 : 0.f;
    float p1 = (lane < 60) ? h2 * w31 : 0.f;
#pragma unroll
    for (int o = 32; o > 0; o >>= 1) { p0 += __shfl_down(p0, o); p1 += __shfl_down(p1, o); }
    if (lane == 0) {
      float s0 = tanhf(p0 + b3[0]);
      float s1 = tanhf(p1 + b3[1]);
      int m = m0 + row;
      int b = m / NS, s = m % NS;
      float* cb = coords + (size_t)b * (2 * NS);
      cb[(s >> 1) * 2 + (s & 1)] = s0;
      cb[(288 + (s >> 1)) * 2 + (s & 1)] = s1;
    }
  }
}

// ---------------- kernel 4: GEMM qkv = x_f16 @ [Wq|Wk|Wv]_f16 ---------------------------------
// 256x256 tile, BK=64, 8 waves (2M x 4N), double-buffered 128 KiB LDS.
// T2: chunk-XOR swizzle (chunk ^= row&7) matched to 16x16x32 fragment reads; staged via
//     linear global_load_lds dest + inverse-swizzled global source (both-sides involution).
// T3/T4: stage tile t+1 BEFORE waiting, then counted s_waitcnt vmcnt(8) (tile t+1's 8 loads
//     stay in flight across the barrier; never vmcnt(0) in the main loop).
// T5: s_setprio(1) around each 16-MFMA phase cluster.
__device__ __forceinline__ void async_copy16(const f16* g, f16* l) {
  __builtin_amdgcn_global_load_lds((const __attribute__((address_space(1))) void*)g,
                                   (__attribute__((address_space(3))) void*)l, 16, 0, 0);
}

__global__ __launch_bounds__(512, 2) void gemm_kernel(const f16* __restrict__ A,   // M_TOT x 768
                                                      const f16* __restrict__ Bt,  // 2304 x 768
                                                      const float* __restrict__ bq,
                                                      const float* __restrict__ bk,
                                                      const float* __restrict__ bv,
                                                      f16* __restrict__ C) {       // M_TOT x 2304
  constexpr int BM = 256, BN = 256, BK = 64;
  constexpr int NKT = ND / BK;                 // 12 K-tiles
  __shared__ __align__(16) f16 sA[2][BM * BK]; // 2 x 32 KB
  __shared__ __align__(16) f16 sB[2][BN * BK]; // 2 x 32 KB   (total 128 KiB)

  int tid = threadIdx.x;
  int lane = tid & 63, wave = tid >> 6;
  int wm = wave >> 2, wn = wave & 3;           // 2 x 4 wave grid; wave tile 128x64
  int bn = blockIdx.x % (N_TOT / BN);          // bn-fast: 9 consecutive blocks share A panel
  int bm = blockIdx.x / (N_TOT / BN);
  int m0 = bm * BM, n0 = bn * BN;
  int r16 = lane & 15, q = lane >> 4;

  // staging geometry: thread t covers LDS bytes [t*16, t*16+16) of each 8 KB round (linear),
  // source global chunk = ldsChunk ^ (row&7)  (row = j*64 + tid>>3, j*64 keeps row&7 fixed)
  int srow = tid >> 3;                         // 0..63
  int schunk = (tid & 7) ^ (srow & 7);
  const f16* gA = A + (size_t)(m0 + srow) * ND + schunk * 8;
  const f16* gB = Bt + (size_t)(n0 + srow) * ND + schunk * 8;

  auto stage = [&](int buf, int kt) {
#pragma unroll
    for (int j = 0; j < 4; j++)
      async_copy16(gA + (size_t)j * 64 * ND + kt * 64, &sA[buf][j * 4096 + tid * 8]);
#pragma unroll
    for (int j = 0; j < 4; j++)
      async_copy16(gB + (size_t)j * 64 * ND + kt * 64, &sB[buf][j * 4096 + tid * 8]);
  };

  f32x4 acc[8][4];
#pragma unroll
  for (int mi = 0; mi < 8; mi++)
#pragma unroll
    for (int ni = 0; ni < 4; ni++) acc[mi][ni] = 0.f;

  stage(0, 0);                                  // prologue: tile 0 -> buf0 (8 loads in flight)

  for (int t = 0; t < NKT; t++) {
    int cur = t & 1;
    if (t + 1 < NKT) {
      stage(cur ^ 1, t + 1);                    // issue next tile first (disjoint buffer)
      asm volatile("s_waitcnt vmcnt(8)" ::: "memory");   // drain tile t; keep t+1 in flight
    } else {
      asm volatile("s_waitcnt vmcnt(0)" ::: "memory");
    }
    asm volatile("s_barrier" ::: "memory");     // all waves' tile-t halves landed

    const f16* pA = sA[cur];
    const f16* pB = sB[cur];

    // B fragments for the whole tile (8 x ds_read_b128), reused by all 4 phases
    f16x8 bF[4][2];
#pragma unroll
    for (int ni = 0; ni < 4; ni++) {
      int R = wn * 64 + ni * 16 + r16;
#pragma unroll
      for (int s = 0; s < 2; s++) {
        int ch = (s * 4 + q) ^ (R & 7);
        bF[ni][s] = *(const f16x8*)(pB + R * 64 + ch * 8);
      }
    }

#pragma unroll
    for (int p = 0; p < 4; p++) {               // phase = 2 m-frags x 4 n-frags x K=64 (16 MFMA)
      f16x8 aF[2][2];
#pragma unroll
      for (int mm = 0; mm < 2; mm++) {
        int R = wm * 128 + (p * 2 + mm) * 16 + r16;
#pragma unroll
        for (int s = 0; s < 2; s++) {
          int ch = (s * 4 + q) ^ (R & 7);
          aF[mm][s] = *(const f16x8*)(pA + R * 64 + ch * 8);
        }
      }
      __builtin_amdgcn_s_setprio(1);
#pragma unroll
      for (int mm = 0; mm < 2; mm++)
#pragma unroll
        for (int ni = 0; ni < 4; ni++) {        // swapped operands -> C^T register layout
          acc[p * 2 + mm][ni] =
              __builtin_amdgcn_mfma_f32_16x16x32_f16(bF[ni][0], aF[mm][0], acc[p * 2 + mm][ni], 0, 0, 0);
          acc[p * 2 + mm][ni] =
              __builtin_amdgcn_mfma_f32_16x16x32_f16(bF[ni][1], aF[mm][1], acc[p * 2 + mm][ni], 0, 0, 0);
        }
      __builtin_amdgcn_s_setprio(0);
    }
    asm volatile("s_barrier" ::: "memory");     // everyone done reading buf[cur] before overwrite
  }

  // epilogue: acc[mi][ni] lane -> C[m = .. + (lane&15)][n = .. + (lane>>4)*4 + r], f16x4 stores
  int m0g = m0 + wm * 128 + r16;
  int n0g = n0 + wn * 64 + q * 4;
#pragma unroll
  for (int mi = 0; mi < 8; mi++) {
    int gm = m0g + mi * 16;
#pragma unroll
    for (int ni = 0; ni < 4; ni++) {
      int gn = n0g + ni * 16;
      const float* bp = (gn < ND) ? (bq + gn)
                      : ((gn < 2 * ND) ? (bk + gn - ND) : (bv + gn - 2 * ND));
      float4 bias = *(const float4*)bp;
      f16x4 o;
      o[0] = (f16)(acc[mi][ni][0] + bias.x);
      o[1] = (f16)(acc[mi][ni][1] + bias.y);
      o[2] = (f16)(acc[mi][ni][2] + bias.z);
      o[3] = (f16)(acc[mi][ni][3] + bias.w);
      *(f16x4*)(C + (size_t)gm * N_TOT + gn) = o;
    }
  }
}

// ---------------- kernel 5: bilinear sample + score + sigmoid*value; XCD-swizzled ------------
// blk&7 -> XCD; each XCD handles 4 batches (21 MB qkv working set vs 85 MB unswizzled).
__global__ __launch_bounds__(256) void sample_kernel(const f16* __restrict__ qkv,
                                                     const float* __restrict__ coords,
                                                     float* __restrict__ out) {
  int wave = threadIdx.x >> 6, t = threadIdx.x & 63;
  int x8 = blockIdx.x & 7;           // XCD heuristic (blockIdx % 8)
  int i = blockIdx.x >> 3;           // 0..575
  int b = x8 * 4 + (i / 144);        // batch
  int p = (i % 144) * 4 + wave;      // point in batch

  float gx = coords[(size_t)b * (2 * NS) + p * 2 + 0];
  float gy = coords[(size_t)b * (2 * NS) + p * 2 + 1];
  float ix = ((gx + 1.f) * (float)NG - 1.f) * 0.5f;
  float iy = ((gy + 1.f) * (float)NG - 1.f) * 0.5f;
  float x0f = floorf(ix), y0f = floorf(iy);
  float wx1 = ix - x0f, wx0 = 1.f - wx1;
  float wy1 = iy - y0f, wy0 = 1.f - wy1;
  int x0 = (int)x0f, y0 = (int)y0f, x1 = x0 + 1, y1 = y0 + 1;
  bool vx0 = (x0 >= 0) & (x0 <= NG - 1), vx1 = (x1 >= 0) & (x1 <= NG - 1);
  bool vy0 = (y0 >= 0) & (y0 <= NG - 1), vy1 = (y1 >= 0) & (y1 <= NG - 1);
  int cx0 = min(max(x0, 0), NG - 1), cx1 = min(max(x1, 0), NG - 1);
  int cy0 = min(max(y0, 0), NG - 1), cy1 = min(max(y1, 0), NG - 1);
  float w00 = wx0 * wy0 * ((vx0 && vy0) ? 1.f : 0.f);
  float w10 = wx1 * wy0 * ((vx1 && vy0) ? 1.f : 0.f);
  float w01 = wx0 * wy1 * ((vx0 && vy1) ? 1.f : 0.f);
  float w11 = wx1 * wy1 * ((vx1 && vy1) ? 1.f : 0.f);

  size_t base = (size_t)b * NS;
  const f16* r00 = qkv + (base + cy0 * NG + cx0) * N_TOT;
  const f16* r10 = qkv + (base + cy0 * NG + cx1) * N_TOT;
  const f16* r01 = qkv + (base + cy1 * NG + cx0) * N_TOT;
  const f16* r11 = qkv + (base + cy1 * NG + cx1) * N_TOT;
  const f16* qr  = qkv + (base + p) * N_TOT;

  int d0 = t * 12;
  float partial = 0.f;
  float outv[12];
#pragma unroll
  for (int ch = 0; ch < 3; ch++) {
    int d = d0 + ch * 4;
    f16x4 k00 = *(const f16x4*)(r00 + ND + d);
    f16x4 k10 = *(const f16x4*)(r10 + ND + d);
    f16x4 k01 = *(const f16x4*)(r01 + ND + d);
    f16x4 k11 = *(const f16x4*)(r11 + ND + d);
    f16x4 v00 = *(const f16x4*)(r00 + 2 * ND + d);
    f16x4 v10 = *(const f16x4*)(r10 + 2 * ND + d);
    f16x4 v01 = *(const f16x4*)(r01 + 2 * ND + d);
    f16x4 v11 = *(const f16x4*)(r11 + 2 * ND + d);
    f16x4 qv  = *(const f16x4*)(qr + d);
#pragma unroll
    for (int j = 0; j < 4; j++) {
      float sk = w00 * (float)k00[j] + w10 * (float)k10[j]
               + w01 * (float)k01[j] + w11 * (float)k11[j];
      float sv = w00 * (float)v00[j] + w10 * (float)v10[j]
               + w01 * (float)v01[j] + w11 * (float)v11[j];
      partial = fmaf((float)qv[j], sk, partial);
      outv[ch * 4 + j] = sv;
    }
  }
#pragma unroll
  for (int o = 32; o > 0; o >>= 1) partial += __shfl_down(partial, o);
  float score = __shfl(partial, 0);
  float sig = 1.f / (1.f + expf(-0.01f * score));
  float* orow = out + (size_t)(base + p) * ND;
#pragma unroll
  for (int ch = 0; ch < 3; ch++) {
    float4 st;
    st.x = sig * outv[ch * 4 + 0]; st.y = sig * outv[ch * 4 + 1];
    st.z = sig * outv[ch * 4 + 2]; st.w = sig * outv[ch * 4 + 3];
    *(float4*)(orow + d0 + ch * 4) = st;
  }
}

extern "C" void kernel_launch(void* const* d_in, const int* in_sizes, int n_in,
                              void* d_out, int out_size, void* d_ws, size_t ws_size,
                              hipStream_t stream) {
  const float* x  = (const float*)d_in[0];
  const float* Wq = (const float*)d_in[2];
  const float* bq = (const float*)d_in[3];
  const float* Wk = (const float*)d_in[4];
  const float* bk = (const float*)d_in[5];
  const float* Wv = (const float*)d_in[6];
  const float* bv = (const float*)d_in[7];
  const float* W1 = (const float*)d_in[8];
  const float* b1 = (const float*)d_in[9];
  const float* W2 = (const float*)d_in[10];
  const float* b2 = (const float*)d_in[11];
  const float* W3 = (const float*)d_in[12];
  const float* b3 = (const float*)d_in[13];
  float* out = (float*)d_out;

  char* ws = (char*)d_ws;
  f16*   xb     = (f16*)(ws);                       // 28,311,552
  f16*   WT     = (f16*)(ws + 28311552);            //  3,538,944
  f16*   qkv    = (f16*)(ws + 31850496);            // 84,934,656
  // pre-gemm scratch carved from qkv region (consumed by z1 BEFORE gemm writes qkv):
  f16*   WcT_hi = (f16*)(ws + 31850496);            //     98,304
  f16*   WcT_lo = (f16*)(ws + 31948800);            //     98,304
  float* bc     = (float*)(ws + 116969472);         //        256
  float* coords = (float*)(ws + 121393408);         //    147,456 (total 121,540,864)

  cast_w_t_kernel<<<dim3(432), dim3(256), 0, stream>>>(Wq, Wk, Wv, WT);
  wcT_kernel<<<dim3(769), dim3(256), 0, stream>>>(Wq, Wk, bq, bk, W1, b1, WcT_hi, WcT_lo, bc);
  z1_fused_kernel<<<dim3(M_TOT / 16), dim3(256), 0, stream>>>(x, WcT_hi, WcT_lo, bc,
                                                              W2, b2, W3, b3, xb, coords);
  gemm_kernel<<<dim3((M_TOT / 256) * (N_TOT / 256)), dim3(512), 0, stream>>>(xb, WT, bq, bk, bv, qkv);
  sample_kernel<<<dim3(M_TOT / 4), dim3(256), 0, stream>>>(qkv, coords, out);
  (void)in_sizes; (void)n_in; (void)out_size; (void)ws_size;
}

// Round 2
// 348.989 us; speedup vs baseline: 1.0292x; 1.0292x over previous
//
#include <hip/hip_runtime.h>

typedef _Float16 f16;
typedef _Float16 f16x8 __attribute__((ext_vector_type(8)));
typedef _Float16 f16x4 __attribute__((ext_vector_type(4)));
typedef float f32x4 __attribute__((ext_vector_type(4)));
typedef float f32x16 __attribute__((ext_vector_type(16)));

constexpr int NB = 32, NS = 576, ND = 768, NG = 24;
constexpr int M_TOT = NB * NS;   // 18432
constexpr int N_TOT = 3 * ND;    // 2304

// ---------------- kernel 1: build W_allT (N_TOT x ND) f16 via LDS tile transpose ----------------
__global__ __launch_bounds__(256) void cast_w_t_kernel(const float* __restrict__ Wq,
                                                       const float* __restrict__ Wk,
                                                       const float* __restrict__ Wv,
                                                       f16* __restrict__ WT) {
  __shared__ float tile[64][65];
  int bt = blockIdx.x;                 // 0..431
  int ntile = bt / 12, ktile = bt % 12;
  const float* src = (ntile < 12) ? Wq : ((ntile < 24) ? Wk : Wv);
  int n0 = (ntile % 12) * 64, k0 = ktile * 64;
  int cc = threadIdx.x & 63, rr = threadIdx.x >> 6;
#pragma unroll
  for (int i = 0; i < 16; i++) {
    int k = rr + i * 4;
    tile[cc][k] = src[(size_t)(k0 + k) * ND + n0 + cc];
  }
  __syncthreads();
#pragma unroll
  for (int i = 0; i < 16; i++) {
    int n = rr + i * 4;
    WT[(size_t)(ntile * 64 + n) * ND + k0 + cc] = (f16)tile[n][cc];
  }
}

// ---------------- kernel 2: WcT hi/lo, j-split x4 per block; bc in block 768 ----------------
__global__ __launch_bounds__(256) void wcT_kernel(const float* __restrict__ Wq,
                                                  const float* __restrict__ Wk,
                                                  const float* __restrict__ bq,
                                                  const float* __restrict__ bk,
                                                  const float* __restrict__ W1,
                                                  const float* __restrict__ b1,
                                                  f16* __restrict__ WcT_hi,
                                                  f16* __restrict__ WcT_lo,
                                                  float* __restrict__ bc) {
  if (blockIdx.x == 768) {
    int c = threadIdx.x;
    if (c < 60) {
      float acc = b1[c];
      for (int j = 0; j < ND; j++)
        acc += bq[j] * W1[j * 60 + c] + bk[j] * W1[(ND + j) * 60 + c];
      bc[c] = acc;
    }
    return;
  }
  __shared__ float part[4][64];
  int r = blockIdx.x;                       // 0..767
  int wave = threadIdx.x >> 6, lane = threadIdx.x & 63;
  int c = (lane < 60) ? lane : 59;
  const float* wq = Wq + (size_t)r * ND;
  const float* wk = Wk + (size_t)r * ND;
  float acc = 0.f;
  int j0 = wave * 192;
  for (int j = j0; j < j0 + 192; j++)
    acc += wq[j] * W1[j * 60 + c] + wk[j] * W1[(ND + j) * 60 + c];
  part[wave][lane] = acc;
  __syncthreads();
  if (wave == 0 && lane < 60) {
    float v = part[0][lane] + part[1][lane] + part[2][lane] + part[3][lane];
    f16 hi = (f16)v;
    WcT_hi[(size_t)lane * ND + r] = hi;
    WcT_lo[(size_t)lane * ND + r] = (f16)(v - (float)hi);
  }
}

// ---------------- kernel 3: fused z1 MFMA + x cast + MLP tail + coord scatter ----------------
__global__ __launch_bounds__(256) void z1_fused_kernel(const float* __restrict__ x,
                                                       const f16* __restrict__ WcT_hi,
                                                       const f16* __restrict__ WcT_lo,
                                                       const float* __restrict__ bc,
                                                       const float* __restrict__ W2,
                                                       const float* __restrict__ b2,
                                                       const float* __restrict__ W3,
                                                       const float* __restrict__ b3,
                                                       f16* __restrict__ xb,
                                                       float* __restrict__ coords) {
  __shared__ float red[3][16][64];   // [wave-1][reg-idx][lane]
  __shared__ float htile[16][60];    // relu(z1) tile for this block's 16 rows
  int wave = threadIdx.x >> 6, lane = threadIdx.x & 63;
  int q = lane >> 4, r16 = lane & 15;
  int m0 = blockIdx.x * 16;
  int k0 = wave * 192;
  const float* xr = x + (size_t)(m0 + r16) * ND + k0;
  f16* xbr = xb + (size_t)(m0 + r16) * ND + k0;

  f32x4 acc[4];
#pragma unroll
  for (int nf = 0; nf < 4; nf++) acc[nf] = 0.f;

  for (int kk = 0; kk < 192; kk += 32) {
    int ko = kk + q * 8;
    float4 v0 = *(const float4*)(xr + ko);
    float4 v1 = *(const float4*)(xr + ko + 4);
    f16x8 a_hi, a_lo;
    float xv[8] = {v0.x, v0.y, v0.z, v0.w, v1.x, v1.y, v1.z, v1.w};
#pragma unroll
    for (int j = 0; j < 8; j++) {
      f16 h = (f16)xv[j];
      a_hi[j] = h;
      a_lo[j] = (f16)(xv[j] - (float)h);
    }
    *(f16x8*)(xbr + ko) = a_hi;      // fused fp32->f16 cast of x
    f16x8 b_hi[4], b_lo[4];
#pragma unroll
    for (int nf = 0; nf < 4; nf++) {
      size_t off = (size_t)(nf * 16 + r16) * ND + k0 + ko;
      b_hi[nf] = *(const f16x8*)(WcT_hi + off);
      b_lo[nf] = *(const f16x8*)(WcT_lo + off);
    }
#pragma unroll
    for (int nf = 0; nf < 4; nf++) {
      acc[nf] = __builtin_amdgcn_mfma_f32_16x16x32_f16(a_hi, b_hi[nf], acc[nf], 0, 0, 0);
      acc[nf] = __builtin_amdgcn_mfma_f32_16x16x32_f16(a_lo, b_hi[nf], acc[nf], 0, 0, 0);
      acc[nf] = __builtin_amdgcn_mfma_f32_16x16x32_f16(a_hi, b_lo[nf], acc[nf], 0, 0, 0);
    }
  }

  if (wave > 0) {
#pragma unroll
    for (int nf = 0; nf < 4; nf++)
#pragma unroll
      for (int r = 0; r < 4; r++) red[wave - 1][nf * 4 + r][lane] = acc[nf][r];
  }
  __syncthreads();
  if (wave == 0) {
#pragma unroll
    for (int nf = 0; nf < 4; nf++) {
      int col = nf * 16 + r16;
      if (col < 60) {
        float bcv = bc[col];
#pragma unroll
        for (int r = 0; r < 4; r++) {
          float v = acc[nf][r] + red[0][nf * 4 + r][lane] + red[1][nf * 4 + r][lane]
                  + red[2][nf * 4 + r][lane] + bcv;
          htile[q * 4 + r][col] = fmaxf(v, 0.f);
        }
      }
    }
  }
  __syncthreads();

  // MLP tail: wave w -> rows 4w..4w+3; lane c<60 owns layer-2 column c.
  int c = (lane < 60) ? lane : 59;
  float b2v = b2[c];
  float w30 = W3[c * 2 + 0], w31 = W3[c * 2 + 1];
#pragma unroll
  for (int rr = 0; rr < 4; rr++) {
    int row = wave * 4 + rr;
    float acc2 = b2v;
    for (int j = 0; j < 60; j++) acc2 = fmaf(htile[row][j], W2[j * 60 + c], acc2);
    float h2 = fmaxf(acc2, 0.f);
    float p0 = (lane < 60) ? h2 * w30 : 0.f;
    float p1 = (lane < 60) ? h2 * w31 : 0.f;
#pragma unroll
    for (int o = 32; o > 0; o >>= 1) { p0 += __shfl_down(p0, o); p1 += __shfl_down(p1, o); }
    if (lane == 0) {
      float s0 = tanhf(p0 + b3[0]);
      float s1 = tanhf(p1 + b3[1]);
      int m = m0 + row;
      int b = m / NS, s = m % NS;
      float* cb = coords + (size_t)b * (2 * NS);
      cb[(s >> 1) * 2 + (s & 1)] = s0;
      cb[(288 + (s >> 1)) * 2 + (s & 1)] = s1;
    }
  }
}

// ---------------- kernel 4: GEMM qkv = x_f16 @ [Wq|Wk|Wv]_f16 ---------------------------------
// 256x256 tile, BK=64, 8 waves (2M x 4N), double-buffered 128 KiB LDS.
// m201-style 4-phase-per-K-tile lockstep: each phase = {4x ds_read aF + 1 half-tile stage
// (2 global_load_lds) -> s_barrier -> sched_barrier(0) -> setprio(1) -> 16 MFMA -> setprio(0)
// -> s_barrier}. Stages always target buf^1 (never read this tile) => race-free regardless of
// barrier placement. Tile boundary: vmcnt(0)+barrier — loads were issued 1-4 phases earlier so
// latency is already covered (this is NOT a fresh-issue drain).
// T1: bijective XCD swizzle (648 = 8*81), bm-major per XCD => disjoint A panels per XCD L2.
__device__ __forceinline__ void async_copy16(const f16* g, f16* l) {
  __builtin_amdgcn_global_load_lds((const __attribute__((address_space(1))) void*)g,
                                   (__attribute__((address_space(3))) void*)l, 16, 0, 0);
}

__global__ __launch_bounds__(512, 2) void gemm_kernel(const f16* __restrict__ A,   // M_TOT x 768
                                                      const f16* __restrict__ Bt,  // 2304 x 768
                                                      const float* __restrict__ bq,
                                                      const float* __restrict__ bk,
                                                      const float* __restrict__ bv,
                                                      f16* __restrict__ C) {       // M_TOT x 2304
  constexpr int BM = 256, BN = 256, BK = 64;
  constexpr int NKT = ND / BK;                 // 12 K-tiles
  __shared__ __align__(16) f16 sA[2][BM * BK]; // 2 x 32 KB
  __shared__ __align__(16) f16 sB[2][BN * BK]; // 2 x 32 KB   (total 128 KiB)

  int tid = threadIdx.x;
  int lane = tid & 63, wave = tid >> 6;
  int wm = wave >> 2, wn = wave & 3;           // 2 x 4 wave grid; wave tile 128x64
  // T1: XCD-contiguous remap. Dispatch round-robins blockIdx over 8 XCDs; give XCD x the
  // contiguous range wg in [81x, 81x+81), bm-major => bm in [9x, 9x+9) disjoint per XCD.
  int orig = blockIdx.x;                       // 0..647
  int wg = (orig & 7) * 81 + (orig >> 3);
  int bm = wg / 9, bn = wg % 9;
  int m0 = bm * BM, n0 = bn * BN;
  int r16 = lane & 15, q = lane >> 4;

  // staging geometry: thread t covers LDS bytes [t*16, t*16+16) of each 8 KB round (linear),
  // source global chunk = ldsChunk ^ (row&7)  (row = j*64 + tid>>3, j*64 keeps row&7 fixed)
  int srow = tid >> 3;                         // 0..63
  int schunk = (tid & 7) ^ (srow & 7);
  const f16* gA = A + (size_t)(m0 + srow) * ND + schunk * 8;
  const f16* gB = Bt + (size_t)(n0 + srow) * ND + schunk * 8;

  auto stage_pair = [&](int buf, int kt, int j) {   // half-tile j: A rows j*64.. + B rows j*64..
    async_copy16(gA + (size_t)j * 64 * ND + kt * 64, &sA[buf][j * 4096 + tid * 8]);
    async_copy16(gB + (size_t)j * 64 * ND + kt * 64, &sB[buf][j * 4096 + tid * 8]);
  };

  f32x4 acc[8][4];
#pragma unroll
  for (int mi = 0; mi < 8; mi++)
#pragma unroll
    for (int ni = 0; ni < 4; ni++) acc[mi][ni] = 0.f;

  // prologue: tile 0 -> buf0 (8 loads), full drain once
#pragma unroll
  for (int j = 0; j < 4; j++) stage_pair(0, 0, j);
  asm volatile("s_waitcnt vmcnt(0)" ::: "memory");
  asm volatile("s_barrier" ::: "memory");

  for (int t = 0; t < NKT; t++) {
    int cur = t & 1;
    const f16* pA = sA[cur];
    const f16* pB = sB[cur];
    bool pf = (t + 1 < NKT);

    // B fragments for the whole tile (8 x ds_read_b128), reused by all 4 phases
    f16x8 bF[4][2];
#pragma unroll
    for (int ni = 0; ni < 4; ni++) {
      int R = wn * 64 + ni * 16 + r16;
#pragma unroll
      for (int s = 0; s < 2; s++) {
        int ch = (s * 4 + q) ^ (R & 7);
        bF[ni][s] = *(const f16x8*)(pB + R * 64 + ch * 8);
      }
    }

#pragma unroll
    for (int p = 0; p < 4; p++) {               // phase = 2 m-frags x 4 n-frags x K=64 (16 MFMA)
      f16x8 aF[2][2];
#pragma unroll
      for (int mm = 0; mm < 2; mm++) {
        int R = wm * 128 + (p * 2 + mm) * 16 + r16;
#pragma unroll
        for (int s = 0; s < 2; s++) {
          int ch = (s * 4 + q) ^ (R & 7);
          aF[mm][s] = *(const f16x8*)(pA + R * 64 + ch * 8);
        }
      }
      if (pf) stage_pair(cur ^ 1, t + 1, p);    // 2 loads into the buffer nobody reads this tile
      asm volatile("s_barrier" ::: "memory");   // all waves enter MFMA section together
      __builtin_amdgcn_sched_barrier(0);        // keep MFMAs after the barrier (lockstep rhythm)
      __builtin_amdgcn_s_setprio(1);
#pragma unroll
      for (int mm = 0; mm < 2; mm++)
#pragma unroll
        for (int ni = 0; ni < 4; ni++) {        // swapped operands -> C^T register layout
          acc[p * 2 + mm][ni] =
              __builtin_amdgcn_mfma_f32_16x16x32_f16(bF[ni][0], aF[mm][0], acc[p * 2 + mm][ni], 0, 0, 0);
          acc[p * 2 + mm][ni] =
              __builtin_amdgcn_mfma_f32_16x16x32_f16(bF[ni][1], aF[mm][1], acc[p * 2 + mm][ni], 0, 0, 0);
        }
      __builtin_amdgcn_s_setprio(0);
      asm volatile("s_barrier" ::: "memory");   // close the MFMA section
    }
    // tile boundary: ensure tile t+1 fully landed (loads issued 1-4 phases ago -> ~no stall)
    if (pf) asm volatile("s_waitcnt vmcnt(0)" ::: "memory");
    asm volatile("s_barrier" ::: "memory");
  }

  // epilogue: acc[mi][ni] lane -> C[m = .. + (lane&15)][n = .. + (lane>>4)*4 + r], f16x4 stores
  int m0g = m0 + wm * 128 + r16;
  int n0g = n0 + wn * 64 + q * 4;
#pragma unroll
  for (int mi = 0; mi < 8; mi++) {
    int gm = m0g + mi * 16;
#pragma unroll
    for (int ni = 0; ni < 4; ni++) {
      int gn = n0g + ni * 16;
      const float* bp = (gn < ND) ? (bq + gn)
                      : ((gn < 2 * ND) ? (bk + gn - ND) : (bv + gn - 2 * ND));
      float4 bias = *(const float4*)bp;
      f16x4 o;
      o[0] = (f16)(acc[mi][ni][0] + bias.x);
      o[1] = (f16)(acc[mi][ni][1] + bias.y);
      o[2] = (f16)(acc[mi][ni][2] + bias.z);
      o[3] = (f16)(acc[mi][ni][3] + bias.w);
      *(f16x4*)(C + (size_t)gm * N_TOT + gn) = o;
    }
  }
}

// ---------------- kernel 5: bilinear sample + score + sigmoid*value; XCD-swizzled ------------
// blk&7 -> XCD; each XCD handles 4 batches (21 MB qkv working set vs 85 MB unswizzled).
__global__ __launch_bounds__(256) void sample_kernel(const f16* __restrict__ qkv,
                                                     const float* __restrict__ coords,
                                                     float* __restrict__ out) {
  int wave = threadIdx.x >> 6, t = threadIdx.x & 63;
  int x8 = blockIdx.x & 7;           // XCD heuristic (blockIdx % 8)
  int i = blockIdx.x >> 3;           // 0..575
  int b = x8 * 4 + (i / 144);        // batch
  int p = (i % 144) * 4 + wave;      // point in batch

  float gx = coords[(size_t)b * (2 * NS) + p * 2 + 0];
  float gy = coords[(size_t)b * (2 * NS) + p * 2 + 1];
  float ix = ((gx + 1.f) * (float)NG - 1.f) * 0.5f;
  float iy = ((gy + 1.f) * (float)NG - 1.f) * 0.5f;
  float x0f = floorf(ix), y0f = floorf(iy);
  float wx1 = ix - x0f, wx0 = 1.f - wx1;
  float wy1 = iy - y0f, wy0 = 1.f - wy1;
  int x0 = (int)x0f, y0 = (int)y0f, x1 = x0 + 1, y1 = y0 + 1;
  bool vx0 = (x0 >= 0) & (x0 <= NG - 1), vx1 = (x1 >= 0) & (x1 <= NG - 1);
  bool vy0 = (y0 >= 0) & (y0 <= NG - 1), vy1 = (y1 >= 0) & (y1 <= NG - 1);
  int cx0 = min(max(x0, 0), NG - 1), cx1 = min(max(x1, 0), NG - 1);
  int cy0 = min(max(y0, 0), NG - 1), cy1 = min(max(y1, 0), NG - 1);
  float w00 = wx0 * wy0 * ((vx0 && vy0) ? 1.f : 0.f);
  float w10 = wx1 * wy0 * ((vx1 && vy0) ? 1.f : 0.f);
  float w01 = wx0 * wy1 * ((vx0 && vy1) ? 1.f : 0.f);
  float w11 = wx1 * wy1 * ((vx1 && vy1) ? 1.f : 0.f);

  size_t base = (size_t)b * NS;
  const f16* r00 = qkv + (base + cy0 * NG + cx0) * N_TOT;
  const f16* r10 = qkv + (base + cy0 * NG + cx1) * N_TOT;
  const f16* r01 = qkv + (base + cy1 * NG + cx0) * N_TOT;
  const f16* r11 = qkv + (base + cy1 * NG + cx1) * N_TOT;
  const f16* qr  = qkv + (base + p) * N_TOT;

  int d0 = t * 12;
  float partial = 0.f;
  float outv[12];
#pragma unroll
  for (int ch = 0; ch < 3; ch++) {
    int d = d0 + ch * 4;
    f16x4 k00 = *(const f16x4*)(r00 + ND + d);
    f16x4 k10 = *(const f16x4*)(r10 + ND + d);
    f16x4 k01 = *(const f16x4*)(r01 + ND + d);
    f16x4 k11 = *(const f16x4*)(r11 + ND + d);
    f16x4 v00 = *(const f16x4*)(r00 + 2 * ND + d);
    f16x4 v10 = *(const f16x4*)(r10 + 2 * ND + d);
    f16x4 v01 = *(const f16x4*)(r01 + 2 * ND + d);
    f16x4 v11 = *(const f16x4*)(r11 + 2 * ND + d);
    f16x4 qv  = *(const f16x4*)(qr + d);
#pragma unroll
    for (int j = 0; j < 4; j++) {
      float sk = w00 * (float)k00[j] + w10 * (float)k10[j]
               + w01 * (float)k01[j] + w11 * (float)k11[j];
      float sv = w00 * (float)v00[j] + w10 * (float)v10[j]
               + w01 * (float)v01[j] + w11 * (float)v11[j];
      partial = fmaf((float)qv[j], sk, partial);
      outv[ch * 4 + j] = sv;
    }
  }
#pragma unroll
  for (int o = 32; o > 0; o >>= 1) partial += __shfl_down(partial, o);
  float score = __shfl(partial, 0);
  float sig = 1.f / (1.f + expf(-0.01f * score));
  float* orow = out + (size_t)(base + p) * ND;
#pragma unroll
  for (int ch = 0; ch < 3; ch++) {
    float4 st;
    st.x = sig * outv[ch * 4 + 0]; st.y = sig * outv[ch * 4 + 1];
    st.z = sig * outv[ch * 4 + 2]; st.w = sig * outv[ch * 4 + 3];
    *(float4*)(orow + d0 + ch * 4) = st;
  }
}

extern "C" void kernel_launch(void* const* d_in, const int* in_sizes, int n_in,
                              void* d_out, int out_size, void* d_ws, size_t ws_size,
                              hipStream_t stream) {
  const float* x  = (const float*)d_in[0];
  const float* Wq = (const float*)d_in[2];
  const float* bq = (const float*)d_in[3];
  const float* Wk = (const float*)d_in[4];
  const float* bk = (const float*)d_in[5];
  const float* Wv = (const float*)d_in[6];
  const float* bv = (const float*)d_in[7];
  const float* W1 = (const float*)d_in[8];
  const float* b1 = (const float*)d_in[9];
  const float* W2 = (const float*)d_in[10];
  const float* b2 = (const float*)d_in[11];
  const float* W3 = (const float*)d_in[12];
  const float* b3 = (const float*)d_in[13];
  float* out = (float*)d_out;

  char* ws = (char*)d_ws;
  f16*   xb     = (f16*)(ws);                       // 28,311,552
  f16*   WT     = (f16*)(ws + 28311552);            //  3,538,944
  f16*   qkv    = (f16*)(ws + 31850496);            // 84,934,656
  // pre-gemm scratch carved from qkv region (consumed by z1 BEFORE gemm writes qkv):
  f16*   WcT_hi = (f16*)(ws + 31850496);            //     98,304
  f16*   WcT_lo = (f16*)(ws + 31948800);            //     98,304
  float* bc     = (float*)(ws + 116969472);         //        256
  float* coords = (float*)(ws + 121393408);         //    147,456 (total 121,540,864)

  cast_w_t_kernel<<<dim3(432), dim3(256), 0, stream>>>(Wq, Wk, Wv, WT);
  wcT_kernel<<<dim3(769), dim3(256), 0, stream>>>(Wq, Wk, bq, bk, W1, b1, WcT_hi, WcT_lo, bc);
  z1_fused_kernel<<<dim3(M_TOT / 16), dim3(256), 0, stream>>>(x, WcT_hi, WcT_lo, bc,
                                                              W2, b2, W3, b3, xb, coords);
  gemm_kernel<<<dim3((M_TOT / 256) * (N_TOT / 256)), dim3(512), 0, stream>>>(xb, WT, bq, bk, bv, qkv);
  sample_kernel<<<dim3(M_TOT / 4), dim3(256), 0, stream>>>(qkv, coords, out);
  (void)in_sizes; (void)n_in; (void)out_size; (void)ws_size;
}

// Round 3
// 320.179 us; speedup vs baseline: 1.1218x; 1.0900x over previous
//
#include <hip/hip_runtime.h>

typedef _Float16 f16;
typedef _Float16 f16x8 __attribute__((ext_vector_type(8)));
typedef _Float16 f16x4 __attribute__((ext_vector_type(4)));
typedef float f32x4 __attribute__((ext_vector_type(4)));
typedef float f32x16 __attribute__((ext_vector_type(16)));

constexpr int NB = 32, NS = 576, ND = 768, NG = 24;
constexpr int M_TOT = NB * NS;   // 18432
constexpr int N_TOT = 3 * ND;    // 2304

// ---------------- kernel 1: build W_allT (N_TOT x ND) f16 via LDS tile transpose ----------------
__global__ __launch_bounds__(256) void cast_w_t_kernel(const float* __restrict__ Wq,
                                                       const float* __restrict__ Wk,
                                                       const float* __restrict__ Wv,
                                                       f16* __restrict__ WT) {
  __shared__ float tile[64][65];
  int bt = blockIdx.x;                 // 0..431
  int ntile = bt / 12, ktile = bt % 12;
  const float* src = (ntile < 12) ? Wq : ((ntile < 24) ? Wk : Wv);
  int n0 = (ntile % 12) * 64, k0 = ktile * 64;
  int cc = threadIdx.x & 63, rr = threadIdx.x >> 6;
#pragma unroll
  for (int i = 0; i < 16; i++) {
    int k = rr + i * 4;
    tile[cc][k] = src[(size_t)(k0 + k) * ND + n0 + cc];
  }
  __syncthreads();
#pragma unroll
  for (int i = 0; i < 16; i++) {
    int n = rr + i * 4;
    WT[(size_t)(ntile * 64 + n) * ND + k0 + cc] = (f16)tile[n][cc];
  }
}

// ---------------- kernel 2: WcT hi/lo, j-split x4 per block; bc in block 768 (parallelized) ----
__global__ __launch_bounds__(256) void wcT_kernel(const float* __restrict__ Wq,
                                                  const float* __restrict__ Wk,
                                                  const float* __restrict__ bq,
                                                  const float* __restrict__ bk,
                                                  const float* __restrict__ W1,
                                                  const float* __restrict__ b1,
                                                  f16* __restrict__ WcT_hi,
                                                  f16* __restrict__ WcT_lo,
                                                  float* __restrict__ bc) {
  __shared__ float part[4][64];
  int wave = threadIdx.x >> 6, lane = threadIdx.x & 63;
  int c = (lane < 60) ? lane : 59;
  int j0 = wave * 192;
  if (blockIdx.x == 768) {
    // bc[c] = b1[c] + sum_j bq[j]*W1[j][c] + bk[j]*W1[ND+j][c], 4-wave j-split
    float acc = 0.f;
    for (int j = j0; j < j0 + 192; j++)
      acc += bq[j] * W1[j * 60 + c] + bk[j] * W1[(ND + j) * 60 + c];
    part[wave][lane] = acc;
    __syncthreads();
    if (wave == 0 && lane < 60)
      bc[lane] = b1[lane] + part[0][lane] + part[1][lane] + part[2][lane] + part[3][lane];
    return;
  }
  int r = blockIdx.x;                       // 0..767
  const float* wq = Wq + (size_t)r * ND;
  const float* wk = Wk + (size_t)r * ND;
  float acc = 0.f;
  for (int j = j0; j < j0 + 192; j++)
    acc += wq[j] * W1[j * 60 + c] + wk[j] * W1[(ND + j) * 60 + c];
  part[wave][lane] = acc;
  __syncthreads();
  if (wave == 0 && lane < 60) {
    float v = part[0][lane] + part[1][lane] + part[2][lane] + part[3][lane];
    f16 hi = (f16)v;
    WcT_hi[(size_t)lane * ND + r] = hi;
    WcT_lo[(size_t)lane * ND + r] = (f16)(v - (float)hi);
  }
}

// ---------------- kernel 3: fused z1 MFMA + x cast + MLP tail + coord scatter ----------------
__global__ __launch_bounds__(256) void z1_fused_kernel(const float* __restrict__ x,
                                                       const f16* __restrict__ WcT_hi,
                                                       const f16* __restrict__ WcT_lo,
                                                       const float* __restrict__ bc,
                                                       const float* __restrict__ W2,
                                                       const float* __restrict__ b2,
                                                       const float* __restrict__ W3,
                                                       const float* __restrict__ b3,
                                                       f16* __restrict__ xb,
                                                       float* __restrict__ coords) {
  __shared__ float red[3][16][64];   // [wave-1][reg-idx][lane]
  __shared__ float htile[16][60];    // relu(z1) tile for this block's 16 rows
  int wave = threadIdx.x >> 6, lane = threadIdx.x & 63;
  int q = lane >> 4, r16 = lane & 15;
  int m0 = blockIdx.x * 16;
  int k0 = wave * 192;
  const float* xr = x + (size_t)(m0 + r16) * ND + k0;
  f16* xbr = xb + (size_t)(m0 + r16) * ND + k0;

  f32x4 acc[4];
#pragma unroll
  for (int nf = 0; nf < 4; nf++) acc[nf] = 0.f;

  for (int kk = 0; kk < 192; kk += 32) {
    int ko = kk + q * 8;
    float4 v0 = *(const float4*)(xr + ko);
    float4 v1 = *(const float4*)(xr + ko + 4);
    f16x8 a_hi, a_lo;
    float xv[8] = {v0.x, v0.y, v0.z, v0.w, v1.x, v1.y, v1.z, v1.w};
#pragma unroll
    for (int j = 0; j < 8; j++) {
      f16 h = (f16)xv[j];
      a_hi[j] = h;
      a_lo[j] = (f16)(xv[j] - (float)h);
    }
    *(f16x8*)(xbr + ko) = a_hi;      // fused fp32->f16 cast of x
    f16x8 b_hi[4], b_lo[4];
#pragma unroll
    for (int nf = 0; nf < 4; nf++) {
      size_t off = (size_t)(nf * 16 + r16) * ND + k0 + ko;
      b_hi[nf] = *(const f16x8*)(WcT_hi + off);
      b_lo[nf] = *(const f16x8*)(WcT_lo + off);
    }
#pragma unroll
    for (int nf = 0; nf < 4; nf++) {
      acc[nf] = __builtin_amdgcn_mfma_f32_16x16x32_f16(a_hi, b_hi[nf], acc[nf], 0, 0, 0);
      acc[nf] = __builtin_amdgcn_mfma_f32_16x16x32_f16(a_lo, b_hi[nf], acc[nf], 0, 0, 0);
      acc[nf] = __builtin_amdgcn_mfma_f32_16x16x32_f16(a_hi, b_lo[nf], acc[nf], 0, 0, 0);
    }
  }

  if (wave > 0) {
#pragma unroll
    for (int nf = 0; nf < 4; nf++)
#pragma unroll
      for (int r = 0; r < 4; r++) red[wave - 1][nf * 4 + r][lane] = acc[nf][r];
  }
  __syncthreads();
  if (wave == 0) {
#pragma unroll
    for (int nf = 0; nf < 4; nf++) {
      int col = nf * 16 + r16;
      if (col < 60) {
        float bcv = bc[col];
#pragma unroll
        for (int r = 0; r < 4; r++) {
          float v = acc[nf][r] + red[0][nf * 4 + r][lane] + red[1][nf * 4 + r][lane]
                  + red[2][nf * 4 + r][lane] + bcv;
          htile[q * 4 + r][col] = fmaxf(v, 0.f);
        }
      }
    }
  }
  __syncthreads();

  // MLP tail: wave w -> rows 4w..4w+3; lane c<60 owns layer-2 column c.
  int c = (lane < 60) ? lane : 59;
  float b2v = b2[c];
  float w30 = W3[c * 2 + 0], w31 = W3[c * 2 + 1];
#pragma unroll
  for (int rr = 0; rr < 4; rr++) {
    int row = wave * 4 + rr;
    float acc2 = b2v;
    for (int j = 0; j < 60; j++) acc2 = fmaf(htile[row][j], W2[j * 60 + c], acc2);
    float h2 = fmaxf(acc2, 0.f);
    float p0 = (lane < 60) ? h2 * w30 : 0.f;
    float p1 = (lane < 60) ? h2 * w31 : 0.f;
#pragma unroll
    for (int o = 32; o > 0; o >>= 1) { p0 += __shfl_down(p0, o); p1 += __shfl_down(p1, o); }
    if (lane == 0) {
      float s0 = tanhf(p0 + b3[0]);
      float s1 = tanhf(p1 + b3[1]);
      int m = m0 + row;
      int b = m / NS, s = m % NS;
      float* cb = coords + (size_t)b * (2 * NS);
      cb[(s >> 1) * 2 + (s & 1)] = s0;
      cb[(288 + (s >> 1)) * 2 + (s & 1)] = s1;
    }
  }
}

// ---------------- kernel 4: GEMM qkv = x_f16 @ [Wq|Wk|Wv]_f16, BK=64, 32x32x16 MFMA ----------
// Round-0 multi-block structure (32 KB LDS -> 2-3 blocks/CU co-resident: cross-block overlap
// hides barrier drains, m114/m97 mechanism). Changes vs round-0:
//  * swizzle f(row) = (row&7) ^ (((row>>3)&3)<<1) mixes row bits [4:3] into the chunk slot
//    -> lanes l, l+8, l+16, l+24 (previous 4-way alias set) now land in distinct 16B slots.
//    Applied on BOTH the pre-swizzled global source and the read XOR (same involution,
//    bit-identical data, arithmetic unchanged).
//  * bijective XCD swizzle: 2592 = 8*324; each XCD owns 18 disjoint bm panels, bn-fast.
__device__ __forceinline__ void async_copy16(const f16* g, f16* l) {
  __builtin_amdgcn_global_load_lds((const __attribute__((address_space(1))) void*)g,
                                   (__attribute__((address_space(3))) void*)l, 16, 0, 0);
}

__global__ __launch_bounds__(256) void gemm_kernel(const f16* __restrict__ A,   // M_TOT x 768
                                                   const f16* __restrict__ Bt,  // 2304 x 768
                                                   const float* __restrict__ bq,
                                                   const float* __restrict__ bk,
                                                   const float* __restrict__ bv,
                                                   f16* __restrict__ C) {       // M_TOT x 2304
  constexpr int BM = 128, BK = 64;
  __shared__ __align__(16) f16 sA[BM * BK];   // 16 KB
  __shared__ __align__(16) f16 sB[BM * BK];   // 16 KB

  // XCD-bijective remap: grid 2592 = 8 XCDs * 324; XCD x gets bm in [18x, 18x+18), bn-fast.
  int orig = blockIdx.x;
  int wg = (orig & 7) * 324 + (orig >> 3);
  int bm = wg / 18, bn = wg % 18;
  int tid = threadIdx.x;
  int wave = tid >> 6, lane = tid & 63;
  int wm = (wave >> 1) * 64, wn = (wave & 1) * 64;
  int m0 = bm * BM, n0 = bn * BM;

  int srow = tid >> 3;                          // 0..31 (row within 32-row staging group)
  int gchunk = ((tid & 7) ^ (srow & 7) ^ (((srow >> 3) & 3) << 1)) * 8;  // swizzled src chunk

  f32x16 acc[2][2];
#pragma unroll
  for (int i = 0; i < 2; i++)
#pragma unroll
    for (int j = 0; j < 2; j++) acc[i][j] = 0.f;

  int r32 = lane & 31, q2 = lane >> 5;          // 32x32 frag: row = lane&31, k-half = lane>>5
  int fx = (r32 & 7) ^ (((r32 >> 3) & 3) << 1); // read-side swizzle (row bits [4:0] -> slot)

  for (int kk = 0; kk < ND; kk += BK) {
#pragma unroll
    for (int ps = 0; ps < 4; ps++) {
      async_copy16(A + (size_t)(m0 + ps * 32 + srow) * ND + kk + gchunk, sA + ps * 2048 + tid * 8);
      async_copy16(Bt + (size_t)(n0 + ps * 32 + srow) * ND + kk + gchunk, sB + ps * 2048 + tid * 8);
    }
    __syncthreads();

#pragma unroll
    for (int ks = 0; ks < 4; ks++) {            // 4 K-steps of 16
      f16x8 aF[2], bF[2];
#pragma unroll
      for (int mt = 0; mt < 2; mt++) {
        int R = wm + mt * 32 + r32;
        aF[mt] = *(const f16x8*)(sA + R * 64 + (((ks * 2 + q2) ^ fx) * 8));
      }
#pragma unroll
      for (int nt = 0; nt < 2; nt++) {
        int R = wn + nt * 32 + r32;
        bF[nt] = *(const f16x8*)(sB + R * 64 + (((ks * 2 + q2) ^ fx) * 8));
      }
#pragma unroll
      for (int mt = 0; mt < 2; mt++)
#pragma unroll
        for (int nt = 0; nt < 2; nt++)   // swapped operands -> C^T register layout
          acc[mt][nt] = __builtin_amdgcn_mfma_f32_32x32x16_f16(bF[nt], aF[mt], acc[mt][nt], 0, 0, 0);
    }
    __syncthreads();
  }

#pragma unroll
  for (int mt = 0; mt < 2; mt++) {
    int gm = m0 + wm + mt * 32 + r32;
#pragma unroll
    for (int nt = 0; nt < 2; nt++) {
#pragma unroll
      for (int g = 0; g < 4; g++) {
        int gn0 = n0 + wn + nt * 32 + 8 * g + 4 * q2;
        const float* bp = (gn0 < ND) ? (bq + gn0)
                        : ((gn0 < 2 * ND) ? (bk + gn0 - ND) : (bv + gn0 - 2 * ND));
        float4 bias = *(const float4*)bp;
        f16x4 o;
        o[0] = (f16)(acc[mt][nt][4 * g + 0] + bias.x);
        o[1] = (f16)(acc[mt][nt][4 * g + 1] + bias.y);
        o[2] = (f16)(acc[mt][nt][4 * g + 2] + bias.z);
        o[3] = (f16)(acc[mt][nt][4 * g + 3] + bias.w);
        *(f16x4*)(C + (size_t)gm * N_TOT + gn0) = o;
      }
    }
  }
}

// ---------------- kernel 5: bilinear sample + score + sigmoid*value; XCD-swizzled ------------
// blk&7 -> XCD; each XCD handles 4 batches. Coalesced channel layout: pass ch covers channels
// [ch*256, ch*256+256) with lane t owning 4 contiguous -> every load/store is a contiguous
// 512B(f16)/1KB(f32) wave transaction (was 24B-stride, ~1/3 efficiency).
__global__ __launch_bounds__(256) void sample_kernel(const f16* __restrict__ qkv,
                                                     const float* __restrict__ coords,
                                                     float* __restrict__ out) {
  int wave = threadIdx.x >> 6, t = threadIdx.x & 63;
  int x8 = blockIdx.x & 7;           // XCD heuristic (blockIdx % 8)
  int i = blockIdx.x >> 3;           // 0..575
  int b = x8 * 4 + (i / 144);        // batch
  int p = (i % 144) * 4 + wave;      // point in batch

  float gx = coords[(size_t)b * (2 * NS) + p * 2 + 0];
  float gy = coords[(size_t)b * (2 * NS) + p * 2 + 1];
  float ix = ((gx + 1.f) * (float)NG - 1.f) * 0.5f;
  float iy = ((gy + 1.f) * (float)NG - 1.f) * 0.5f;
  float x0f = floorf(ix), y0f = floorf(iy);
  float wx1 = ix - x0f, wx0 = 1.f - wx1;
  float wy1 = iy - y0f, wy0 = 1.f - wy1;
  int x0 = (int)x0f, y0 = (int)y0f, x1 = x0 + 1, y1 = y0 + 1;
  bool vx0 = (x0 >= 0) & (x0 <= NG - 1), vx1 = (x1 >= 0) & (x1 <= NG - 1);
  bool vy0 = (y0 >= 0) & (y0 <= NG - 1), vy1 = (y1 >= 0) & (y1 <= NG - 1);
  int cx0 = min(max(x0, 0), NG - 1), cx1 = min(max(x1, 0), NG - 1);
  int cy0 = min(max(y0, 0), NG - 1), cy1 = min(max(y1, 0), NG - 1);
  float w00 = wx0 * wy0 * ((vx0 && vy0) ? 1.f : 0.f);
  float w10 = wx1 * wy0 * ((vx1 && vy0) ? 1.f : 0.f);
  float w01 = wx0 * wy1 * ((vx0 && vy1) ? 1.f : 0.f);
  float w11 = wx1 * wy1 * ((vx1 && vy1) ? 1.f : 0.f);

  size_t base = (size_t)b * NS;
  const f16* r00 = qkv + (base + cy0 * NG + cx0) * N_TOT;
  const f16* r10 = qkv + (base + cy0 * NG + cx1) * N_TOT;
  const f16* r01 = qkv + (base + cy1 * NG + cx0) * N_TOT;
  const f16* r11 = qkv + (base + cy1 * NG + cx1) * N_TOT;
  const f16* qr  = qkv + (base + p) * N_TOT;

  float partial = 0.f;
  float outv[12];
#pragma unroll
  for (int ch = 0; ch < 3; ch++) {
    int d = ch * 256 + t * 4;        // coalesced: wave covers 256 contiguous channels
    f16x4 k00 = *(const f16x4*)(r00 + ND + d);
    f16x4 k10 = *(const f16x4*)(r10 + ND + d);
    f16x4 k01 = *(const f16x4*)(r01 + ND + d);
    f16x4 k11 = *(const f16x4*)(r11 + ND + d);
    f16x4 v00 = *(const f16x4*)(r00 + 2 * ND + d);
    f16x4 v10 = *(const f16x4*)(r10 + 2 * ND + d);
    f16x4 v01 = *(const f16x4*)(r01 + 2 * ND + d);
    f16x4 v11 = *(const f16x4*)(r11 + 2 * ND + d);
    f16x4 qv  = *(const f16x4*)(qr + d);
#pragma unroll
    for (int j = 0; j < 4; j++) {
      float sk = w00 * (float)k00[j] + w10 * (float)k10[j]
               + w01 * (float)k01[j] + w11 * (float)k11[j];
      float sv = w00 * (float)v00[j] + w10 * (float)v10[j]
               + w01 * (float)v01[j] + w11 * (float)v11[j];
      partial = fmaf((float)qv[j], sk, partial);
      outv[ch * 4 + j] = sv;
    }
  }
#pragma unroll
  for (int o = 32; o > 0; o >>= 1) partial += __shfl_down(partial, o);
  float score = __shfl(partial, 0);
  float sig = 1.f / (1.f + expf(-0.01f * score));
  float* orow = out + (size_t)(base + p) * ND;
#pragma unroll
  for (int ch = 0; ch < 3; ch++) {
    int d = ch * 256 + t * 4;
    float4 st;
    st.x = sig * outv[ch * 4 + 0]; st.y = sig * outv[ch * 4 + 1];
    st.z = sig * outv[ch * 4 + 2]; st.w = sig * outv[ch * 4 + 3];
    *(float4*)(orow + d) = st;
  }
}

extern "C" void kernel_launch(void* const* d_in, const int* in_sizes, int n_in,
                              void* d_out, int out_size, void* d_ws, size_t ws_size,
                              hipStream_t stream) {
  const float* x  = (const float*)d_in[0];
  const float* Wq = (const float*)d_in[2];
  const float* bq = (const float*)d_in[3];
  const float* Wk = (const float*)d_in[4];
  const float* bk = (const float*)d_in[5];
  const float* Wv = (const float*)d_in[6];
  const float* bv = (const float*)d_in[7];
  const float* W1 = (const float*)d_in[8];
  const float* b1 = (const float*)d_in[9];
  const float* W2 = (const float*)d_in[10];
  const float* b2 = (const float*)d_in[11];
  const float* W3 = (const float*)d_in[12];
  const float* b3 = (const float*)d_in[13];
  float* out = (float*)d_out;

  char* ws = (char*)d_ws;
  f16*   xb     = (f16*)(ws);                       // 28,311,552
  f16*   WT     = (f16*)(ws + 28311552);            //  3,538,944
  f16*   qkv    = (f16*)(ws + 31850496);            // 84,934,656
  // pre-gemm scratch carved from qkv region (consumed by z1 BEFORE gemm writes qkv):
  f16*   WcT_hi = (f16*)(ws + 31850496);            //     98,304
  f16*   WcT_lo = (f16*)(ws + 31948800);            //     98,304
  float* bc     = (float*)(ws + 116969472);         //        256
  float* coords = (float*)(ws + 121393408);         //    147,456 (total 121,540,864)

  cast_w_t_kernel<<<dim3(432), dim3(256), 0, stream>>>(Wq, Wk, Wv, WT);
  wcT_kernel<<<dim3(769), dim3(256), 0, stream>>>(Wq, Wk, bq, bk, W1, b1, WcT_hi, WcT_lo, bc);
  z1_fused_kernel<<<dim3(M_TOT / 16), dim3(256), 0, stream>>>(x, WcT_hi, WcT_lo, bc,
                                                              W2, b2, W3, b3, xb, coords);
  gemm_kernel<<<dim3((M_TOT / 128) * (N_TOT / 128)), dim3(256), 0, stream>>>(xb, WT, bq, bk, bv, qkv);
  sample_kernel<<<dim3(M_TOT / 4), dim3(256), 0, stream>>>(qkv, coords, out);
  (void)in_sizes; (void)n_in; (void)out_size; (void)ws_size;
}